// Round 13
// baseline (505.525 us; speedup 1.0000x reference)
//
#include <hip/hip_runtime.h>

#define LL    128
#define STR   131          // odd; row-contiguous streams; group bases spread mod 32
#define NT    512          // 8 waves = 1 wave per tile
#define T     16
#define NTILE 8
#define SCRN  768          // per-wave scratch floats: [0,256)=accB, [256,512)=M0, [512,768)=sp

__device__ __forceinline__ float softplus_f(float x) { return log1pf(__expf(x)); }

// Block-wide barrier that only drains LDS (global prefetches stay in flight).
__device__ __forceinline__ void lds_barrier() {
    asm volatile("s_waitcnt lgkmcnt(0)" ::: "memory");
    __builtin_amdgcn_s_barrier();
    asm volatile("" ::: "memory");
}
// Wave-internal ordering for closure micro-steps: wave is lockstep, so
// lgkmcnt(0) + compiler fence suffices — no s_barrier.
__device__ __forceinline__ void wave_lds_fence() {
    asm volatile("s_waitcnt lgkmcnt(0)" ::: "memory");
    __builtin_amdgcn_sched_barrier(0);
}

// LDS layout:
//   ALs[r*STR+c], c>=r : A[r][c] (incl diag);  c<r : A[c][r] (transposed mirror)
//   SLs[r*STR+c]       : S[r][c] during inside (diag=0), overwritten in place
//                        with SL = S - log G as cells finalize in the outside
//                        pass; mirrored like ALs.
//   SCR[ww*768 ...]    : per-wave scratch (bulk acc, bulk shift M0, softplus)
extern "C" __global__ __launch_bounds__(NT, 1) void cky_kernel(
    const float* __restrict__ scores,
    const int* __restrict__ seq_lens,
    float* __restrict__ Z_out,
    float* __restrict__ marg_out)
{
    extern __shared__ float smem[];
    float* ALs = smem;                    // 128*131
    float* SLs = smem + LL * STR;         // 128*131
    float* SCR = smem + 2 * LL * STR;     // 8*768

    const int b    = blockIdx.x;
    const int tid  = threadIdx.x;
    const int ww   = tid >> 6;            // wave id = tile slot
    const int lane = tid & 63;
    const int go   = lane >> 2;           // group 0..15 (owns tile row u=go)
    const int vl   = lane & 3;            // lane within group
    const float* s = scores + (size_t)b * LL * LL;
    float* marg = marg_out + (size_t)b * LL * LL;
    const int len = seq_lens[b];          // full-128 DP; len only gates root/output
    float* scr = SCR + ww * SCRN;

    // ---- init: diagonal A = softplus(s_ii); S diag = 0 ----
    if (tid < LL) {
        const float sp = softplus_f(s[tid * LL + tid]);
        ALs[tid * STR + tid] = sp;
        SLs[tid * STR + tid] = 0.f;
    }
    lds_barrier();

    // ================= INSIDE: d0 tiles (one wave per tile, no barriers) ====
    {
        const int sI = ww * T;
        const int i  = sI + go;
        float spv[4];
        #pragma unroll
        for (int t = 0; t < 4; ++t) {
            const int idx = lane * 4 + t;
            spv[t] = s[(sI + (idx >> 4)) * LL + (sI + (idx & 15))];
        }
        #pragma unroll
        for (int t = 0; t < 4; ++t)
            scr[512 + lane * 4 + t] = softplus_f(spv[t]);
        wave_lds_fence();
        for (int off = 1; off <= 15; ++off) {
            const int v = go + off;
            const bool act = (v <= 15);
            float acc = 0.f, M = 0.f;
            const int j = sI + v;
            if (act) {
                M = ALs[i * STR + (j - 1)];            // fresh from off-1
                for (int k = i + vl; k < j; k += 4)    // all splits in-tile
                    acc += __expf(ALs[i * STR + k] + ALs[j * STR + (k + 1)] - M);
            }
            acc += __shfl_xor(acc, 1); acc += __shfl_xor(acc, 2);
            if (act && vl == 0) {
                const float S = M + __logf(acc);       // acc >= exp(A[j,j]) >= 1
                const float A = S + scr[512 + go * 16 + v];
                ALs[i * STR + j] = A;  ALs[j * STR + i] = A;
                SLs[i * STR + j] = S;  SLs[j * STR + i] = S;
            }
            wave_lds_fence();
        }
    }
    lds_barrier();

    // ================= INSIDE: tile-diagonals d = 1..7 =================
    for (int d = 1; d < NTILE; ++d) {
        if (ww + d < NTILE) {
            const int I = ww, J = ww + d;
            const int sI = I * T, eI = sI + T, sJ = J * T;
            const int i = sI + go;
            float spv[4];
            #pragma unroll
            for (int t = 0; t < 4; ++t) {
                const int idx = lane * 4 + t;
                spv[t] = s[(sI + (idx >> 4)) * LL + (sJ + (idx & 15))];
            }
            // ---- bulk: splits k in [eI-1, sJ) land in finished tiles ----
            for (int v = 0; v < T; ++v) {
                const int j = sJ + v;
                const float M0 = ALs[i * STR + (eI - 1)] + ALs[j * STR + eI];
                float acc = 0.f;
                for (int k = eI - 1 + vl; k < sJ; k += 4)
                    acc += __expf(ALs[i * STR + k] + ALs[j * STR + (k + 1)] - M0);
                acc += __shfl_xor(acc, 1); acc += __shfl_xor(acc, 2);
                if (vl == 0) { scr[v * 16 + go] = acc; scr[256 + v * 16 + go] = M0; }
            }
            #pragma unroll
            for (int t = 0; t < 4; ++t)
                scr[512 + lane * 4 + t] = softplus_f(spv[t]);
            wave_lds_fence();
            // ---- closure: 31 wave-internal micro-steps, ascending width ----
            for (int off = -15; off <= 15; ++off) {
                const int v = go + off;
                const bool act = (v >= 0) && (v <= 15);
                float acc = 0.f, M0 = 0.f;
                const int j = sJ + v;
                if (act) {
                    M0 = scr[256 + v * 16 + go];
                    // BUGFIX (R12): bulk acc is already group-reduced; load it
                    // in ONE lane only, else the shfl reduce counts it 4x.
                    acc = (vl == 0) ? scr[v * 16 + go] : 0.f;
                    // left-pending: k in [i, eI-1): partner (k+1, j) fresh in-tile
                    for (int k = i + vl; k < eI - 1; k += 4)
                        acc += __expf(ALs[i * STR + k] + ALs[j * STR + (k + 1)] - M0);
                    // right-pending: k in [sJ, j): (i,k) fresh in-tile, (k+1,j) in (J,J)
                    for (int k = sJ + vl; k < j; k += 4)
                        acc += __expf(ALs[i * STR + k] + ALs[j * STR + (k + 1)] - M0);
                }
                acc += __shfl_xor(acc, 1); acc += __shfl_xor(acc, 2);
                if (act && vl == 0) {
                    const float S = M0 + __logf(acc);  // acc >= 1 (bulk k=eI-1 term)
                    const float A = S + scr[512 + go * 16 + v];
                    ALs[i * STR + j] = A;  ALs[j * STR + i] = A;
                    SLs[i * STR + j] = S;  SLs[j * STR + i] = S;
                }
                wave_lds_fence();
            }
        }
        lds_barrier();
    }

    // ================= OUTSIDE: tile-diagonals d = 7..0 (gather) ============
    // G[r,c] = sum over parents; term = exp(A_own + A_sibling - SL_parent) <= 1.
    // SL = S - log G overwrites SLs in place as cells finalize. Cells beyond
    // len get G = 0 -> SL = +inf -> contribute exact 0 downstream.
    for (int d = NTILE - 1; d >= 0; --d) {
        if (ww + d < NTILE) {
            const int I = ww, J = ww + d;
            const int sI = I * T, sJ = J * T, eJ = sJ + T;
            const int r = sI + go;
            // ---- bulk: parents in finished (larger-d) tiles ----
            for (int v = 0; v < T; ++v) {
                const int c = sJ + v;
                const float Aown = ALs[r * STR + c];
                float acc = 0.f;
                for (int Jp = eJ + vl; Jp < LL; Jp += 4)       // left-parents (r, Jp)
                    acc += __expf(Aown + ALs[(c + 1) * STR + Jp] - SLs[r * STR + Jp]);
                for (int Ip = vl; Ip < sI; Ip += 4)            // right-parents (Ip, c)
                    acc += __expf(ALs[(r - 1) * STR + Ip] + Aown - SLs[c * STR + Ip]);
                acc += __shfl_xor(acc, 1); acc += __shfl_xor(acc, 2);
                if (vl == 0) scr[v * 16 + go] = acc;
            }
            wave_lds_fence();
            // ---- closure: descending width; in-tile parents are fresh ----
            const int offLo = (d == 0) ? 0 : -15;
            for (int off = 15; off >= offLo; --off) {
                const int v = go + off;
                const bool act = (v >= 0) && (v <= 15);
                float acc = 0.f, Aown = 0.f, Sown = 0.f;
                const int c = sJ + v;
                if (act) {
                    Aown = ALs[r * STR + c];
                    Sown = SLs[r * STR + c];                   // still S here
                    // BUGFIX (R12): load group-reduced bulk acc in one lane only.
                    acc  = (vl == 0) ? scr[v * 16 + go] : 0.f;
                    for (int Jp = c + 1 + vl; Jp < eJ; Jp += 4)    // in-tile left-parents
                        acc += __expf(Aown + ALs[(c + 1) * STR + Jp] - SLs[r * STR + Jp]);
                    for (int Ip = sI + vl; Ip < r; Ip += 4)        // in-tile right-parents
                        acc += __expf(ALs[(r - 1) * STR + Ip] + Aown - SLs[c * STR + Ip]);
                }
                acc += __shfl_xor(acc, 1); acc += __shfl_xor(acc, 2);
                if (act && vl == 0) {
                    if (r == 0 && c == len - 1) acc += 1.f;    // root seed
                    const float SL = Sown - __logf(acc);       // log(0)=-inf -> SL=+inf ok
                    SLs[r * STR + c] = SL;  SLs[c * STR + r] = SL;
                }
                wave_lds_fence();
            }
        }
        lds_barrier();
    }

    // ================= epilogue: Z + marg (coalesced) =================
    if (tid == 0) Z_out[b] = ALs[len - 1];                     // A[0][len-1]
    for (int idx = tid; idx < LL * LL; idx += NT) {
        const int rr = idx >> 7, cc = idx & (LL - 1);
        float m = 0.f;
        if (cc >= rr && cc < len) {
            const float sp = softplus_f(s[idx]);
            const float G  = __expf(ALs[rr * STR + cc] - sp - SLs[rr * STR + cc]);
            m = G * (1.f - __expf(-sp));                       // G * sigmoid(s)
        }
        marg[idx] = m;
    }
}

extern "C" void kernel_launch(void* const* d_in, const int* in_sizes, int n_in,
                              void* d_out, int out_size, void* d_ws, size_t ws_size,
                              hipStream_t stream) {
    const float* scores  = (const float*)d_in[0];
    const int* seq_lens  = (const int*)d_in[1];
    const int B = in_sizes[1];              // 32
    float* out = (float*)d_out;
    float* Z_out = out;                     // B floats
    float* marg  = out + B;                 // B*L*L floats

    const size_t lds_bytes = (size_t)(2 * LL * STR + NTILE * SCRN) * sizeof(float); // 158720 B
    hipFuncSetAttribute((const void*)cky_kernel,
                        hipFuncAttributeMaxDynamicSharedMemorySize,
                        (int)lds_bytes);
    cky_kernel<<<B, NT, lds_bytes, stream>>>(scores, seq_lens, Z_out, marg);
}

// Round 14
// 266.602 us; speedup vs baseline: 1.8962x; 1.8962x over previous
//
#include <hip/hip_runtime.h>

#define LL  128
#define STR 131            // odd; rows contiguous; cross-group strides spread mod 32
#define NT  1024

__device__ __forceinline__ float softplus_f(float x) { return log1pf(__expf(x)); }

// LDS-visibility-only barrier (no vmcnt drain).
__device__ __forceinline__ void lds_barrier() {
    asm volatile("s_waitcnt lgkmcnt(0)" ::: "memory");
    __builtin_amdgcn_s_barrier();
    asm volatile("" ::: "memory");
}

// LDS:
//  ALs[r*STR+c], c>=r : A[r][c] (incl diag); c<r : A[c][r] (transposed mirror)
//  SBs[r*STR+c], c>r  : S[r][c] during inside, overwritten with SL = S - log G
//                       as the cell finalizes in the outside pass
//  SBs[c*STR+r], r<c  : softplus(s[r][c])  (preloaded; no global reads in loops)
// Pipeline: each phase FINALIZES width w (bulk-carry + the 2 previous-phase
// terms) and BULK-computes width w+1 from >=2-phase-old data (off the chain).
extern "C" __global__ __launch_bounds__(NT, 1) void cky_kernel(
    const float* __restrict__ scores,
    const int* __restrict__ seq_lens,
    float* __restrict__ Z_out,
    float* __restrict__ marg_out)
{
    extern __shared__ float smem[];
    float* ALs = smem;
    float* SBs = smem + LL * STR;

    const int b   = blockIdx.x;
    const int tid = threadIdx.x;
    const int i   = tid >> 3;          // group id = cell row (fixed across phases)
    const int vl  = tid & 7;           // lane within 8-lane group
    const float* s = scores + (size_t)b * LL * LL;
    float* marg = marg_out + (size_t)b * LL * LL;
    const int len = seq_lens[b];

    // ---- init: preload softplus into SBs lower; diag A ----
    for (int idx = tid; idx < LL * LL; idx += NT) {
        const int r = idx >> 7, c = idx & 127;
        const float sp = softplus_f(s[idx]);
        if (c > r)       SBs[c * STR + r] = sp;
        else if (c == r) ALs[r * STR + r] = sp;
    }
    lds_barrier();

    const float Ai = ALs[i * STR + i];          // A[i][i], constant per group

    // ================= INSIDE =================
    float bulk = 0.f, Mreg = Ai;                // carry for next finalize
    // phase w=1: single-term cells, exact
    if (i + 1 < len) {
        const int j = i + 1;
        const float S = Ai + ALs[j * STR + j];
        const float A = S + SBs[j * STR + i];
        if (vl == 0) {
            ALs[i * STR + j] = A;
            ALs[j * STR + i] = A;
            SBs[i * STR + j] = S;
        }
    }
    lds_barrier();

    // phases w = 2 .. len-1: finalize w, bulk for w+1
    for (int w = 2; w < len; ++w) {
        const int j = i + w;
        float a_jm1 = 0.f;
        if (j < len) {
            a_jm1 = ALs[i * STR + (j - 1)];              // fresh (width w-1)
            const float a_ip1j = ALs[j * STR + (i + 1)]; // fresh (width w-1, mirror)
            const float a_jj   = ALs[j * STR + j];       // old diag
            const float spv    = SBs[j * STR + i];       // sp(i,j), old
            const float acc = bulk
                            + __expf(Ai    + a_ip1j - Mreg)   // k = i
                            + __expf(a_jm1 + a_jj   - Mreg);  // k = j-1
            const float S = Mreg + __logf(acc);          // acc >= exp(A[j][j]) > 1
            const float A = S + spv;
            if (vl == 0) {
                ALs[i * STR + j] = A;
                ALs[j * STR + i] = A;
                SBs[i * STR + j] = S;
            }
        }
        // bulk for width w+1 (cell (i, j+1)): k in [i+1, j-1], shift M = A[i,j-1]
        float nb = 0.f;
        if (j + 1 < len) {
            const float M = a_jm1;
            const float* Arow = ALs + i * STR;           // A[i][k]
            const float* Amir = ALs + (j + 1) * STR;     // A[k+1][j+1] via mirror row
            for (int k = i + 1 + vl; k <= j - 1; k += 8)
                nb += __expf(Arow[k] + Amir[k + 1] - M);
        }
        nb += __shfl_xor(nb, 1); nb += __shfl_xor(nb, 2); nb += __shfl_xor(nb, 4);
        bulk = nb; Mreg = a_jm1;
        lds_barrier();
    }

    if (tid == 0) Z_out[b] = ALs[len - 1];               // A[0][len-1]

    // ================= OUTSIDE (gather, pipelined) =================
    // Width len-1 is the root alone: G=1 -> SL = S - log 1 = S, already in place.
    // Loop w = len-2 .. 0: finalize width w (gbulk + 2 fresh width-(w+1) terms),
    // bulk for width w-1 over parents of width >= w+1 (old data).
    const float Arm1 = (i >= 1) ? ALs[(i - 1) * STR + (i - 1)] : 0.f;
    float gbulk = 0.f;                                   // parents widths >= len: none
    for (int w = len - 2; w >= 0; --w) {
        const int c = i + w;
        if (c < len) {
            const float Aown  = ALs[i * STR + c];                // old
            const float S_own = (w == 0) ? 0.f : SBs[i * STR + c]; // old (still S)
            float acc = gbulk;
            if (c + 1 < len) {                                   // parent (i, c+1)
                const float slL  = SBs[i * STR + (c + 1)];       // fresh SL (w+1)
                const float a_c1 = ALs[(c + 1) * STR + (c + 1)]; // diag, old
                acc += __expf(Aown + a_c1 - slL);
            }
            if (i >= 1) {                                        // parent (i-1, c)
                const float slR = SBs[(i - 1) * STR + c];        // fresh SL (w+1)
                acc += __expf(Arm1 + Aown - slR);
            }
            const float SL = S_own - __logf(acc);                // acc==0 -> SL=+inf ok
            if (vl == 0) SBs[i * STR + c] = SL;
        }
        // bulk for width w-1 (cell (i, c2)): parents widths >= w+1 (old SLs)
        float nb = 0.f;
        if (w >= 1) {
            const int c2 = i + w - 1;
            if (c2 < len) {
                const float Ao2 = ALs[i * STR + c2];
                const float* ArowC = ALs + (c2 + 1) * STR;   // A[c2+1][J]
                const float* SLrow = SBs + i * STR;          // SL[i][J]
                for (int J = c2 + 2 + vl; J < len; J += 8)   // left-parents (i, J)
                    nb += __expf(Ao2 + ArowC[J] - SLrow[J]);
                if (i >= 2) {
                    const float* Amir = ALs + (i - 1) * STR; // A[I][i-1] via mirror
                    for (int I = vl; I <= i - 2; I += 8)     // right-parents (I, c2)
                        nb += __expf(Amir[I] + Ao2 - SBs[I * STR + c2]);
                }
            }
        }
        nb += __shfl_xor(nb, 1); nb += __shfl_xor(nb, 2); nb += __shfl_xor(nb, 4);
        gbulk = nb;
        lds_barrier();
    }

    // ================= epilogue: marg = G * sigmoid(s) =================
    for (int idx = tid; idx < LL * LL; idx += NT) {
        const int r = idx >> 7, c = idx & 127;
        float m = 0.f;
        if (c >= r && c < len) {
            const float sp = softplus_f(s[idx]);
            const float G  = __expf(ALs[r * STR + c] - sp - SBs[r * STR + c]);
            m = G * (1.f - __expf(-sp));
        }
        marg[idx] = m;
    }
}

extern "C" void kernel_launch(void* const* d_in, const int* in_sizes, int n_in,
                              void* d_out, int out_size, void* d_ws, size_t ws_size,
                              hipStream_t stream) {
    const float* scores  = (const float*)d_in[0];
    const int* seq_lens  = (const int*)d_in[1];
    const int B = in_sizes[1];              // 32
    float* out = (float*)d_out;
    float* Z_out = out;                     // B floats
    float* marg  = out + B;                 // B*L*L floats

    const size_t lds_bytes = (size_t)2 * LL * STR * sizeof(float);  // 134144 B
    hipFuncSetAttribute((const void*)cky_kernel,
                        hipFuncAttributeMaxDynamicSharedMemorySize,
                        (int)lds_bytes);
    cky_kernel<<<B, NT, lds_bytes, stream>>>(scores, seq_lens, Z_out, marg);
}